// Round 3
// baseline (1665.287 us; speedup 1.0000x reference)
//
#include <hip/hip_runtime.h>

#define NB_ 16
#define TQ_ 2048
#define TS_ 2048
#define DH_ 1024
#define QB_ 32
#define SB_ 64
#define NT_ 512

typedef _Float16 f16x8 __attribute__((ext_vector_type(8)));
typedef _Float16 f16x4 __attribute__((ext_vector_type(4)));
typedef float f32x4 __attribute__((ext_vector_type(4)));

__global__ void convert_f32_f16(const float* __restrict__ src, _Float16* __restrict__ dst) {
  size_t i = ((size_t)blockIdx.x * blockDim.x + threadIdx.x) * 8;
  float4 v0 = *(const float4*)(src + i);
  float4 v1 = *(const float4*)(src + i + 4);
  f16x8 o;
  o[0] = (_Float16)v0.x; o[1] = (_Float16)v0.y; o[2] = (_Float16)v0.z; o[3] = (_Float16)v0.w;
  o[4] = (_Float16)v1.x; o[5] = (_Float16)v1.y; o[6] = (_Float16)v1.z; o[7] = (_Float16)v1.w;
  *(f16x8*)(dst + i) = o;
}

template<bool WS16>
__device__ inline f16x8 ld8(const _Float16* __restrict__ hp, const float* __restrict__ fp, size_t idx) {
  if constexpr (WS16) {
    return *(const f16x8*)(hp + idx);
  } else {
    float4 a = *(const float4*)(fp + idx);
    float4 b = *(const float4*)(fp + idx + 4);
    f16x8 t;
    t[0] = (_Float16)a.x; t[1] = (_Float16)a.y; t[2] = (_Float16)a.z; t[3] = (_Float16)a.w;
    t[4] = (_Float16)b.x; t[5] = (_Float16)b.y; t[6] = (_Float16)b.z; t[7] = (_Float16)b.w;
    return t;
  }
}

// LDS layout identical to v2 (passed correctness):
//   vt     : 0      .. 65536   per-wave private V-transpose buffers, 8 x 8192
//   s_tiles: 65536  .. 102400  8 tiles [(sh*4+dw)][32 q][36] f32
//   p_base : 102400 .. 106496  P [32 q][64 s] f16, swizzled
//   m/l/c  : 106496 .. 106880  softmax state
template<bool WS16>
__global__ __launch_bounds__(NT_, 2)
void attn_v3(const float* __restrict__ hid,
             const float* __restrict__ enc,
             const _Float16* __restrict__ encH,
             float* __restrict__ out) {
  __shared__ __attribute__((aligned(16))) char smem[106880];
  char*  const vt_all  = smem;
  float* const s_tiles = (float*)(smem + 65536);
  char*  const p_base  = smem + 102400;
  float* const m_lds   = (float*)(smem + 106496);
  float* const l_lds   = m_lds + 32;
  float* const c_lds   = m_lds + 64;

  const int tid  = threadIdx.x;
  const int lane = tid & 63;
  const int wid  = tid >> 6;
  const int arow = lane & 15;
  const int agrp = lane >> 4;

  // XCD-affine block mapping: XCD x serves batches 2x, 2x+1
  const int bi = blockIdx.x;
  const int x  = bi & 7;
  const int j  = bi >> 3;
  const int r  = j >> 5;
  const int b  = x * 2 + (r >> 1);
  const int q0 = ((j & 31) + ((r & 1) << 5)) * QB_;

  const int dw = wid & 3;   // QK^T d-chunk (256 wide)
  const int sh = wid >> 2;  // QK^T s-half (32 wide)
  const int hw = wid;       // PV h-chunk (128 wide)

  if (tid < 32) { m_lds[tid] = -__builtin_inff(); l_lds[tid] = 0.0f; }

  // ---- Q fragments in registers (persistent) ----
  f16x8 a_q[2][8];
  #pragma unroll
  for (int m = 0; m < 2; ++m) {
    #pragma unroll
    for (int kf = 0; kf < 8; ++kf) {
      const float* qp = hid + ((size_t)(b * TQ_ + q0 + m * 16 + arow)) * DH_
                            + dw * 256 + kf * 32 + agrp * 8;
      float4 v0 = *(const float4*)qp;
      float4 v1 = *(const float4*)(qp + 4);
      f16x8 t;
      t[0] = (_Float16)v0.x; t[1] = (_Float16)v0.y; t[2] = (_Float16)v0.z; t[3] = (_Float16)v0.w;
      t[4] = (_Float16)v1.x; t[5] = (_Float16)v1.y; t[6] = (_Float16)v1.z; t[7] = (_Float16)v1.w;
      a_q[m][kf] = t;
    }
  }

  f32x4 o_acc[2][8];
  #pragma unroll
  for (int m = 0; m < 2; ++m)
    #pragma unroll
    for (int n = 0; n < 8; ++n)
      o_acc[m][n] = {};

  char* const vt = vt_all + wid * 8192;
  const size_t enc_b = (size_t)b * TS_ * DH_;
  const int h8 = (lane & 15) * 8;
  const int spb = (lane >> 4) * 2;

  // Cross-tile prefetch state: first-half K frags + phase-0 V frags
  f16x8 kpre[2][4];
  f16x8 stA[4][2];

  auto preK = [&](int s0) {
    #pragma unroll
    for (int kf = 0; kf < 4; ++kf) {
      size_t kb = enc_b + (size_t)(s0 + sh * 32 + arow) * DH_ + dw * 256 + kf * 32 + agrp * 8;
      kpre[0][kf] = ld8<WS16>(encH, enc, kb);
      kpre[1][kf] = ld8<WS16>(encH, enc, kb + (size_t)16 * DH_);
    }
  };
  auto preA = [&](int s0) {
    #pragma unroll
    for (int it = 0; it < 4; ++it) {
      size_t base = enc_b + (size_t)(s0 + it * 8 + spb) * DH_ + hw * 128 + h8;
      stA[it][0] = ld8<WS16>(encH, enc, base);
      stA[it][1] = ld8<WS16>(encH, enc, base + DH_);
    }
  };

  preK(0);
  preA(0);

  for (int st = 0; st < TS_ / SB_; ++st) {
    const int s0 = st * SB_;

    // ---- QK^T: issue second-half K loads, then MFMA (first half already resident) ----
    f16x8 krest[2][4];
    #pragma unroll
    for (int kf = 0; kf < 4; ++kf) {
      size_t kb = enc_b + (size_t)(s0 + sh * 32 + arow) * DH_ + dw * 256 + (kf + 4) * 32 + agrp * 8;
      krest[0][kf] = ld8<WS16>(encH, enc, kb);
      krest[1][kf] = ld8<WS16>(encH, enc, kb + (size_t)16 * DH_);
    }

    f32x4 sacc[2][2] = {{{}, {}}, {{}, {}}};
    __builtin_amdgcn_s_setprio(1);
    #pragma unroll
    for (int kf = 0; kf < 4; ++kf) {
      sacc[0][0] = __builtin_amdgcn_mfma_f32_16x16x32_f16(a_q[0][kf], kpre[0][kf], sacc[0][0], 0, 0, 0);
      sacc[0][1] = __builtin_amdgcn_mfma_f32_16x16x32_f16(a_q[0][kf], kpre[1][kf], sacc[0][1], 0, 0, 0);
      sacc[1][0] = __builtin_amdgcn_mfma_f32_16x16x32_f16(a_q[1][kf], kpre[0][kf], sacc[1][0], 0, 0, 0);
      sacc[1][1] = __builtin_amdgcn_mfma_f32_16x16x32_f16(a_q[1][kf], kpre[1][kf], sacc[1][1], 0, 0, 0);
    }
    #pragma unroll
    for (int kf = 0; kf < 4; ++kf) {
      sacc[0][0] = __builtin_amdgcn_mfma_f32_16x16x32_f16(a_q[0][kf + 4], krest[0][kf], sacc[0][0], 0, 0, 0);
      sacc[0][1] = __builtin_amdgcn_mfma_f32_16x16x32_f16(a_q[0][kf + 4], krest[1][kf], sacc[0][1], 0, 0, 0);
      sacc[1][0] = __builtin_amdgcn_mfma_f32_16x16x32_f16(a_q[1][kf + 4], krest[0][kf], sacc[1][0], 0, 0, 0);
      sacc[1][1] = __builtin_amdgcn_mfma_f32_16x16x32_f16(a_q[1][kf + 4], krest[1][kf], sacc[1][1], 0, 0, 0);
    }
    __builtin_amdgcn_s_setprio(0);

    // write partial S tile (sh*4+dw): [32 q][36] f32
    {
      float* tp = s_tiles + (size_t)(sh * 4 + dw) * (32 * 36);
      #pragma unroll
      for (int m = 0; m < 2; ++m)
        #pragma unroll
        for (int n = 0; n < 2; ++n)
          #pragma unroll
          for (int i2 = 0; i2 < 4; ++i2)
            tp[(m * 16 + agrp * 4 + i2) * 36 + n * 16 + arow] = sacc[m][n][i2];
    }

    __syncthreads();  // b1: S complete

    // ---- online softmax ----
    {
      int q = tid >> 4, sq = tid & 15;
      int shh = sq >> 3, sc = (sq & 7) * 4;
      const float* basep = s_tiles + (size_t)shh * 4 * (32 * 36) + q * 36 + sc;
      f32x4 v = *(const f32x4*)basep;
      v += *(const f32x4*)(basep + 1152);
      v += *(const f32x4*)(basep + 2304);
      v += *(const f32x4*)(basep + 3456);
      float mx = fmaxf(fmaxf(v[0], v[1]), fmaxf(v[2], v[3]));
      #pragma unroll
      for (int o = 8; o; o >>= 1) mx = fmaxf(mx, __shfl_xor(mx, o));
      float mprev = m_lds[q];
      float mnew  = fmaxf(mprev, mx);
      float p0 = __expf(v[0] - mnew), p1 = __expf(v[1] - mnew);
      float p2 = __expf(v[2] - mnew), p3 = __expf(v[3] - mnew);
      float ps = (p0 + p1) + (p2 + p3);
      #pragma unroll
      for (int o = 8; o; o >>= 1) ps += __shfl_xor(ps, o);
      if (sq == 0) {
        float cf = __expf(mprev - mnew);
        m_lds[q] = mnew;
        l_lds[q] = l_lds[q] * cf + ps;
        c_lds[q] = cf;
      }
      f16x4 pw;
      pw[0] = (_Float16)p0; pw[1] = (_Float16)p1;
      pw[2] = (_Float16)p2; pw[3] = (_Float16)p3;
      *(f16x4*)(p_base + ((q * 128 + sq * 8) ^ ((q & 7) << 4))) = pw;
    }

    __syncthreads();  // b2: P + m/l/c complete

    // ---- rescale O ----
    #pragma unroll
    for (int m = 0; m < 2; ++m)
      #pragma unroll
      for (int i2 = 0; i2 < 4; ++i2) {
        float cf = c_lds[m * 16 + agrp * 4 + i2];
        #pragma unroll
        for (int n = 0; n < 8; ++n) o_acc[m][n][i2] *= cf;
      }

    // ---- PV phase 0: issue stB loads, hoist P reads, write Vt from stA, MFMA ----
    f16x8 stB[4][2];
    #pragma unroll
    for (int it = 0; it < 4; ++it) {
      size_t base = enc_b + (size_t)(s0 + 32 + it * 8 + spb) * DH_ + hw * 128 + h8;
      stB[it][0] = ld8<WS16>(encH, enc, base);
      stB[it][1] = ld8<WS16>(encH, enc, base + DH_);
    }
    f16x8 pa0  = *(const f16x8*)(p_base + (((arow) * 128 + agrp * 16) ^ ((arow & 7) << 4)));
    f16x8 pa1  = *(const f16x8*)(p_base + (((16 + arow) * 128 + agrp * 16) ^ ((arow & 7) << 4)));
    f16x8 pa0b = *(const f16x8*)(p_base + (((arow) * 128 + 64 + agrp * 16) ^ ((arow & 7) << 4)));
    f16x8 pa1b = *(const f16x8*)(p_base + (((16 + arow) * 128 + 64 + agrp * 16) ^ ((arow & 7) << 4)));

    #pragma unroll
    for (int it = 0; it < 4; ++it) {
      int sp = it * 8 + spb;
      #pragma unroll
      for (int jj = 0; jj < 8; ++jj) {
        int hloc = h8 + jj;
        union { _Float16 h[2]; uint32_t u; } pk;
        pk.h[0] = stA[it][0][jj]; pk.h[1] = stA[it][1][jj];
        *(uint32_t*)(vt + ((hloc * 64 + sp * 2) ^ (((hloc >> 3) & 7) << 4))) = pk.u;
      }
    }
    __builtin_amdgcn_s_setprio(1);
    #pragma unroll
    for (int n = 0; n < 8; ++n) {
      int hloc = n * 16 + arow;
      f16x8 bv = *(const f16x8*)(vt + ((hloc * 64 + agrp * 16) ^ (((hloc >> 3) & 7) << 4)));
      o_acc[0][n] = __builtin_amdgcn_mfma_f32_16x16x32_f16(pa0, bv, o_acc[0][n], 0, 0, 0);
      o_acc[1][n] = __builtin_amdgcn_mfma_f32_16x16x32_f16(pa1, bv, o_acc[1][n], 0, 0, 0);
    }
    __builtin_amdgcn_s_setprio(0);

    // ---- PV phase 1: preload next tile's K/V, write Vt from stB, MFMA ----
    if (st + 1 < TS_ / SB_) {
      preK(s0 + SB_);
      preA(s0 + SB_);
    }
    #pragma unroll
    for (int it = 0; it < 4; ++it) {
      int sp = it * 8 + spb;
      #pragma unroll
      for (int jj = 0; jj < 8; ++jj) {
        int hloc = h8 + jj;
        union { _Float16 h[2]; uint32_t u; } pk;
        pk.h[0] = stB[it][0][jj]; pk.h[1] = stB[it][1][jj];
        *(uint32_t*)(vt + ((hloc * 64 + sp * 2) ^ (((hloc >> 3) & 7) << 4))) = pk.u;
      }
    }
    __builtin_amdgcn_s_setprio(1);
    #pragma unroll
    for (int n = 0; n < 8; ++n) {
      int hloc = n * 16 + arow;
      f16x8 bv = *(const f16x8*)(vt + ((hloc * 64 + agrp * 16) ^ (((hloc >> 3) & 7) << 4)));
      o_acc[0][n] = __builtin_amdgcn_mfma_f32_16x16x32_f16(pa0b, bv, o_acc[0][n], 0, 0, 0);
      o_acc[1][n] = __builtin_amdgcn_mfma_f32_16x16x32_f16(pa1b, bv, o_acc[1][n], 0, 0, 0);
    }
    __builtin_amdgcn_s_setprio(0);
  }

  // ---- epilogue: O / l ----
  #pragma unroll
  for (int m = 0; m < 2; ++m) {
    #pragma unroll
    for (int i2 = 0; i2 < 4; ++i2) {
      int qr = m * 16 + agrp * 4 + i2;
      float inv = 1.0f / l_lds[qr];
      #pragma unroll
      for (int n = 0; n < 8; ++n) {
        out[((size_t)(b * TQ_ + q0 + qr)) * DH_ + hw * 128 + n * 16 + arow] =
            o_acc[m][n][i2] * inv;
      }
    }
  }
}

extern "C" void kernel_launch(void* const* d_in, const int* in_sizes, int n_in,
                              void* d_out, int out_size, void* d_ws, size_t ws_size,
                              hipStream_t stream) {
  (void)in_sizes; (void)n_in; (void)out_size;
  const float* hid = (const float*)d_in[0];
  const float* enc = (const float*)d_in[1];
  float* out = (float*)d_out;

  const size_t encN = (size_t)NB_ * TS_ * DH_;
  const bool ws16 = (ws_size >= encN * sizeof(_Float16));

  dim3 grid(NB_ * (TQ_ / QB_), 1, 1);
  dim3 block(NT_, 1, 1);

  if (ws16) {
    _Float16* encH = (_Float16*)d_ws;
    convert_f32_f16<<<dim3((unsigned)(encN / 8 / 256)), dim3(256), 0, stream>>>(enc, encH);
    attn_v3<true><<<grid, block, 0, stream>>>(hid, enc, encH, out);
  } else {
    attn_v3<false><<<grid, block, 0, stream>>>(hid, enc, nullptr, out);
  }
}